// Round 2
// 230.347 us; speedup vs baseline: 1.1302x; 1.1302x over previous
//
#include <hip/hip_runtime.h>

// CRF loss, B=512, S=1024, L=64 (+start/end -> C=66).
// MFMA formulation: 16 chains (batches, sorted by seq_len) per wave as the
// 16 columns of mfma_f32_16x16x32_f16.  Per step: Y = ET^T X (8 MFMA),
// Y *= exp(pred_t) per (state,chain), renorm by per-chain max, LDS roundtrip
// C/D->B layout, + readout-row MFMA (A = exp(T[.][end]) replicated) captured
// at t = sl_c-1 per chain.  Sequence split into K=64 chunks (min chunk len
// QMIN=12 keeps the rank-1/Birkhoff composition error at mixing^12 ~1e-10),
// composed rank-1: forward chunk from ones + full-chunk backward stub for
// the left vector (chunk len <= 16 <= STUB so the stub is exact).
// Combine kernel assembles answers + gold path, lane-parallel over chunks.
// (Round 1: resubmit of round-0 source — bench failure was an infra flake,
//  audit found no OOB / deadlock / capture hazards.)
constexpr int B_ = 512, S_ = 1024, L_ = 64, C_ = 66;
constexpr int K_ = 64, G_ = 32, STUB = 16, QMIN = 12;

typedef _Float16 half8 __attribute__((ext_vector_type(8)));
typedef float f32x4 __attribute__((ext_vector_type(4)));

__global__ void zero_out_k(float* o){ *o = 0.0f; }

__device__ __forceinline__ f32x4 mfma16(half8 a, half8 b, f32x4 c){
  return __builtin_amdgcn_mfma_f32_16x16x32_f16(a, b, c, 0, 0, 0);
}

__device__ __forceinline__ float max4(const f32x4& a){
  return fmaxf(fmaxf(a[0], a[1]), fmaxf(a[2], a[3]));
}

// ---- bitonic sort of batches by seq_len (stable via idx in low bits) ----
__global__ __launch_bounds__(512) void sort_k(const int* __restrict__ seqlen,
                                              int* __restrict__ order){
  __shared__ int key[B_];
  const int i = threadIdx.x;
  key[i] = (seqlen[i] << 10) | i;
  __syncthreads();
  for (int kk = 2; kk <= B_; kk <<= 1)
    for (int j = kk >> 1; j > 0; j >>= 1){
      const int p = i ^ j;
      if (p > i){
        const int a = key[i], b = key[p];
        if ((a > b) == ((i & kk) == 0)){ key[i] = b; key[p] = a; }
      }
      __syncthreads();
    }
  order[i] = key[i] & 1023;
}

// ---- main: one wave per (group g, chunk k) ----
__global__ __launch_bounds__(64) void crf_chunks_k(
    const float* __restrict__ pred, const int* __restrict__ seqlen,
    const float* __restrict__ trans, const int* __restrict__ order,
    float* __restrict__ wq, float* __restrict__ vhq,
    float* __restrict__ Zfq, float* __restrict__ Rq)
{
  const int g = blockIdx.x / K_;
  const int k = blockIdx.x - g * K_;
  const int lane = threadIdx.x;
  const int c  = lane & 15;        // chain / MFMA column
  const int q4 = lane >> 4;        // quad

  const int myb  = order[g * 16 + c];
  const int mysl = seqlen[myb];
  int msl = mysl;
#pragma unroll
  for (int off = 1; off < 16; off <<= 1){
    const int o = __shfl_xor(msl, off); msl = msl > o ? msl : o;
  }
  const int N  = msl - 1;                     // group's forward steps
  int q  = (N + K_ - 1) / K_;                 // rows per chunk
  if (q < QMIN) q = QMIN;                     // rank-1 accuracy floor
  const int r0 = 1 + k * q;                   // first row of this chunk
  int len = N - k * q; if (len < 0) len = 0; if (len > q) len = q;
  if (k > 0 && len == 0) return;              // inactive chunk (never read)

  const float* pb = pred + (size_t)myb * (S_ * L_);
  __shared__ float lds[16 * 68];
  float* lw = &lds[68 * c];
  const f32x4 z4 = {0.f, 0.f, 0.f, 0.f};

  // ---------- backward stub (k>0): left direction of this chunk ----------
  if (k > 0 && len > 0){
    half8 Ab[4][2];
#pragma unroll
    for (int T = 0; T < 2; ++T)
#pragma unroll
      for (int R = 0; R < 4; ++R){
        half8 v;
#pragma unroll
        for (int jj = 0; jj < 8; ++jj)
          v[jj] = (_Float16)__expf(trans[(16*R + c)*C_ + 32*T + 8*q4 + jj]);
        Ab[R][T] = v;
      }
    float vf[16];
#pragma unroll
    for (int i = 0; i < 16; ++i) vf[i] = 1.0f;
    const int n = (len < STUB) ? len : STUB;  // q<=16 => full-chunk backward
    for (int s = 0; s < n; ++s){
      const int t = r0 + n - 1 - s;
      const f32x4* pl = (const f32x4*)(pb + (size_t)t * L_);
      const f32x4 p0 = pl[2*q4], p1 = pl[2*q4+1], p2 = pl[8+2*q4], p3 = pl[8+2*q4+1];
      half8 X0, X1;
#pragma unroll
      for (int jj = 0; jj < 4; ++jj){
        X0[jj]   = (_Float16)(vf[jj]      * __expf(p0[jj]));
        X0[jj+4] = (_Float16)(vf[jj+4]   * __expf(p1[jj]));
        X1[jj]   = (_Float16)(vf[jj+8]   * __expf(p2[jj]));
        X1[jj+4] = (_Float16)(vf[jj+12]  * __expf(p3[jj]));
      }
      f32x4 a0=z4, a1=z4, a2=z4, a3=z4;
      a0 = mfma16(Ab[0][0],X0,a0); a0 = mfma16(Ab[0][1],X1,a0);
      a1 = mfma16(Ab[1][0],X0,a1); a1 = mfma16(Ab[1][1],X1,a1);
      a2 = mfma16(Ab[2][0],X0,a2); a2 = mfma16(Ab[2][1],X1,a2);
      a3 = mfma16(Ab[3][0],X0,a3); a3 = mfma16(Ab[3][1],X1,a3);
      float mx = fmaxf(fmaxf(max4(a0), max4(a1)), fmaxf(max4(a2), max4(a3)));
      mx = fmaxf(mx, __shfl_xor(mx, 16)); mx = fmaxf(mx, __shfl_xor(mx, 32));
      const float ri = __builtin_amdgcn_rcpf(mx);
      *(f32x4*)&lw[ 0 + 4*q4] = a0 * ri;
      *(f32x4*)&lw[16 + 4*q4] = a1 * ri;
      *(f32x4*)&lw[32 + 4*q4] = a2 * ri;
      *(f32x4*)&lw[48 + 4*q4] = a3 * ri;
      asm volatile("s_waitcnt lgkmcnt(0)" ::: "memory");
      const f32x4 b0 = *(const f32x4*)&lw[8*q4];
      const f32x4 b1 = *(const f32x4*)&lw[8*q4 + 4];
      const f32x4 b2 = *(const f32x4*)&lw[32 + 8*q4];
      const f32x4 b3 = *(const f32x4*)&lw[32 + 8*q4 + 4];
#pragma unroll
      for (int jj = 0; jj < 4; ++jj){
        vf[jj] = b0[jj]; vf[jj+4] = b1[jj]; vf[jj+8] = b2[jj]; vf[jj+12] = b3[jj];
      }
    }
    float* dst = vhq + ((size_t)(g*K_ + k)*16 + c)*64;
    f32x4 o0 = {vf[0],vf[1],vf[2],vf[3]},   o1 = {vf[4],vf[5],vf[6],vf[7]};
    f32x4 o2 = {vf[8],vf[9],vf[10],vf[11]}, o3 = {vf[12],vf[13],vf[14],vf[15]};
    *(f32x4*)&dst[8*q4] = o0; *(f32x4*)&dst[8*q4+4] = o1;
    *(f32x4*)&dst[32+8*q4] = o2; *(f32x4*)&dst[32+8*q4+4] = o3;
  }

  // ---------- forward A-frags + readout frags ----------
  half8 Af[4][2], Ar[2];
#pragma unroll
  for (int T = 0; T < 2; ++T){
#pragma unroll
    for (int R = 0; R < 4; ++R){
      half8 v;
#pragma unroll
      for (int jj = 0; jj < 8; ++jj)
        v[jj] = (_Float16)__expf(trans[(32*T + 8*q4 + jj)*C_ + 16*R + c]);
      Af[R][T] = v;
    }
    half8 vr;
#pragma unroll
    for (int jj = 0; jj < 8; ++jj)
      vr[jj] = (_Float16)__expf(trans[(32*T + 8*q4 + jj)*C_ + (L_ + 1)]);
    Ar[T] = vr;
  }

  // ---------- init state ----------
  half8 X0, X1;
  float Z = 0.0f, Rsv = 0.0f;
  if (k == 0){
    const f32x4* pl = (const f32x4*)pb;   // pred row 0
    const f32x4 p0 = pl[2*q4], p1 = pl[2*q4+1], p2 = pl[8+2*q4], p3 = pl[8+2*q4+1];
    const float* ts = trans + L_ * C_;    // T[start][.]
    float av[16];
#pragma unroll
    for (int jj = 0; jj < 4; ++jj){
      av[jj]    = p0[jj] + ts[8*q4 + jj];
      av[jj+4]  = p1[jj] + ts[8*q4 + 4 + jj];
      av[jj+8]  = p2[jj] + ts[32 + 8*q4 + jj];
      av[jj+12] = p3[jj] + ts[32 + 8*q4 + 4 + jj];
    }
    float mx = av[0];
#pragma unroll
    for (int i = 1; i < 16; ++i) mx = fmaxf(mx, av[i]);
    mx = fmaxf(mx, __shfl_xor(mx, 16)); mx = fmaxf(mx, __shfl_xor(mx, 32));
    Z = mx;
#pragma unroll
    for (int jj = 0; jj < 4; ++jj){
      X0[jj]   = (_Float16)__expf(av[jj]    - mx);
      X0[jj+4] = (_Float16)__expf(av[jj+4]  - mx);
      X1[jj]   = (_Float16)__expf(av[jj+8]  - mx);
      X1[jj+4] = (_Float16)__expf(av[jj+12] - mx);
    }
    f32x4 ro = z4; ro = mfma16(Ar[0], X0, ro); ro = mfma16(Ar[1], X1, ro);
    const float lg = __logf(ro[0]) + Z;
    if (mysl == 1) Rsv = lg;           // sl==1: answer from init state
  } else {
#pragma unroll
    for (int jj = 0; jj < 8; ++jj){ X0[jj] = (_Float16)1.0f; X1[jj] = (_Float16)1.0f; }
  }

  // ---------- forward chunk ----------
  if (len > 0){
    const int tmax = r0 + len - 1;
    auto ldraw = [&](f32x4* raw, int t){
      const int tt = (t > tmax) ? tmax : t;
      const f32x4* pl = (const f32x4*)(pb + (size_t)tt * L_);
      raw[0] = pl[q4]; raw[1] = pl[4+q4]; raw[2] = pl[8+q4]; raw[3] = pl[12+q4];
    };
    f32x4 rA[4], rB[4];
    ldraw(rA, r0); ldraw(rB, r0 + 1);

    auto dostep = [&](f32x4* raw, int t){
      f32x4 a0=z4, a1=z4, a2=z4, a3=z4;
      a0 = mfma16(Af[0][0],X0,a0); a0 = mfma16(Af[0][1],X1,a0);
      a1 = mfma16(Af[1][0],X0,a1); a1 = mfma16(Af[1][1],X1,a1);
      a2 = mfma16(Af[2][0],X0,a2); a2 = mfma16(Af[2][1],X1,a2);
      a3 = mfma16(Af[3][0],X0,a3); a3 = mfma16(Af[3][1],X1,a3);
#pragma unroll
      for (int r = 0; r < 4; ++r){
        a0[r] *= __expf(raw[0][r]); a1[r] *= __expf(raw[1][r]);
        a2[r] *= __expf(raw[2][r]); a3[r] *= __expf(raw[3][r]);
      }
      ldraw(raw, t + 2);                       // prefetch
      float mx = fmaxf(fmaxf(max4(a0), max4(a1)), fmaxf(max4(a2), max4(a3)));
      mx = fmaxf(mx, __shfl_xor(mx, 16)); mx = fmaxf(mx, __shfl_xor(mx, 32));
      const float ri = __builtin_amdgcn_rcpf(mx);
      Z += __logf(mx);
      *(f32x4*)&lw[ 0 + 4*q4] = a0 * ri;
      *(f32x4*)&lw[16 + 4*q4] = a1 * ri;
      *(f32x4*)&lw[32 + 4*q4] = a2 * ri;
      *(f32x4*)&lw[48 + 4*q4] = a3 * ri;
      asm volatile("s_waitcnt lgkmcnt(0)" ::: "memory");
      const f32x4 b0 = *(const f32x4*)&lw[8*q4];
      const f32x4 b1 = *(const f32x4*)&lw[8*q4 + 4];
      const f32x4 b2 = *(const f32x4*)&lw[32 + 8*q4];
      const f32x4 b3 = *(const f32x4*)&lw[32 + 8*q4 + 4];
#pragma unroll
      for (int jj = 0; jj < 4; ++jj){
        X0[jj] = (_Float16)b0[jj]; X0[jj+4] = (_Float16)b1[jj];
        X1[jj] = (_Float16)b2[jj]; X1[jj+4] = (_Float16)b3[jj];
      }
      if (__any(t == mysl - 1)){               // readout only when captured
        f32x4 ro = z4; ro = mfma16(Ar[0], X0, ro); ro = mfma16(Ar[1], X1, ro);
        const float lg = __logf(ro[0]) + Z;
        Rsv = (t == mysl - 1) ? lg : Rsv;      // per-chain capture
      }
    };

    int s = 0;
    while (s < len){
      dostep(rA, r0 + s); ++s;
      if (s >= len) break;
      dostep(rB, r0 + s); ++s;
    }
    // store w = final normalized state (still in LDS)
    float* dst = wq + ((size_t)(g*K_ + k)*16 + c)*64;
    *(f32x4*)&dst[8*q4]      = *(const f32x4*)&lw[8*q4];
    *(f32x4*)&dst[8*q4+4]    = *(const f32x4*)&lw[8*q4 + 4];
    *(f32x4*)&dst[32+8*q4]   = *(const f32x4*)&lw[32 + 8*q4];
    *(f32x4*)&dst[32+8*q4+4] = *(const f32x4*)&lw[32 + 8*q4 + 4];
  }

  if (lane < 16){
    Zfq[(g*K_ + k)*16 + c] = Z;
    Rq [(g*K_ + k)*16 + c] = Rsv;
  }
}

// ---- combine + gold: one wave per sorted position, lane-parallel chunks ----
__global__ __launch_bounds__(64) void crf_combine_k(
    const float* __restrict__ pred, const int* __restrict__ ref,
    const int* __restrict__ seqlen, const float* __restrict__ trans,
    const int* __restrict__ order, const float* __restrict__ wq,
    const float* __restrict__ vhq, const float* __restrict__ Zfq,
    const float* __restrict__ Rq, float* __restrict__ out)
{
  const int p = blockIdx.x, lane = threadIdx.x;
  const int g = p >> 4, c = p & 15;
  const int myb = order[p];
  const int sl  = seqlen[myb];
  int msl = seqlen[order[g*16 + (lane & 15)]];
#pragma unroll
  for (int off = 1; off < 16; off <<= 1){
    const int o = __shfl_xor(msl, off); msl = msl > o ? msl : o;
  }
  const int N = msl - 1;
  int q = (N + K_ - 1) / K_;
  if (q < QMIN) q = QMIN;
  const int kc = (sl <= 1) ? 0 : (sl - 2) / q;   // kc <= 63 < 64 lanes

  // lane l owns boundary l: contrib = log(v_l . w_{l-1}) - log(v_l . 1) + Zf[l-1]
  float contrib = 0.0f;
  if (lane >= 1 && lane <= kc){
    const float* vv = vhq + ((size_t)(g*K_ + lane)*16 + c)*64;
    const float* ww = wq  + ((size_t)(g*K_ + lane - 1)*16 + c)*64;
    float d1 = 0.0f, d0 = 0.0f;
#pragma unroll
    for (int j = 0; j < 16; ++j){
      const f32x4 a = *(const f32x4*)&vv[4*j];
      const f32x4 b = *(const f32x4*)&ww[4*j];
#pragma unroll
      for (int r = 0; r < 4; ++r){ d1 += a[r]*b[r]; d0 += a[r]; }
    }
    contrib = __logf(d1) - __logf(d0) + Zfq[(g*K_ + lane - 1)*16 + c];
  }
  if (lane == 0) contrib = Rq[(g*K_ + kc)*16 + c];

  // gold path
  const float* prow = pred + (size_t)myb * (S_ * L_);
  const int* rrow = ref + (size_t)myb * S_;
  float gold = 0.0f;
  for (int tt = lane; tt < sl; tt += 64){
    const int r = rrow[tt];
    float x = prow[tt * L_ + r];
    const int pr = (tt == 0) ? L_ : rrow[tt - 1];
    x += trans[pr * C_ + r];
    if (tt == sl - 1) x += trans[r * C_ + (L_ + 1)];
    gold += x;
  }
  float val = contrib - gold;
#pragma unroll
  for (int off = 32; off >= 1; off >>= 1) val += __shfl_xor(val, off);
  if (lane == 0) atomicAdd(out, val);
}

extern "C" void kernel_launch(void* const* d_in, const int* in_sizes, int n_in,
                              void* d_out, int out_size, void* d_ws, size_t ws_size,
                              hipStream_t stream) {
  const float* pred   = (const float*)d_in[0];
  const int*   ref    = (const int*)d_in[1];
  const int*   seqlen = (const int*)d_in[2];
  const float* trans  = (const float*)d_in[3];
  float* out = (float*)d_out;

  int*   order = (int*)d_ws;
  float* base  = (float*)d_ws;
  float* w  = base + 1024;            // [G][K][16][64]  (8.4 MB)
  float* vh = w + G_*K_*16*64;        // [G][K][16][64]  (8.4 MB)
  float* Zf = vh + G_*K_*16*64;       // [G][K][16]
  float* Rr = Zf + G_*K_*16;          // [G][K][16]

  zero_out_k<<<1, 1, 0, stream>>>(out);
  sort_k<<<1, 512, 0, stream>>>(seqlen, order);
  crf_chunks_k<<<G_*K_, 64, 0, stream>>>(pred, seqlen, trans, order, w, vh, Zf, Rr);
  crf_combine_k<<<B_, 64, 0, stream>>>(pred, ref, seqlen, trans, order, w, vh, Zf, Rr, out);
}

// Round 3
// 230.001 us; speedup vs baseline: 1.1319x; 1.0015x over previous
//
#include <hip/hip_runtime.h>

// CRF loss, B=512, S=1024, L=64 (+start/end -> C=66).
// MFMA formulation: 16 chains (sorted batches) per wave as the 16 columns of
// mfma_f32_16x16x32_f16.  K=64 chunks (QMIN=12), rank-1 (Birkhoff) stitching:
// forward-from-ones + full-chunk backward stub per chunk.
// Round 3: deferred-norm f16 LDS roundtrip — write UNNORMALIZED MFMA output
// as f16 (RTN cvts), fmax/shfl/rcp runs concurrently with the roundtrip,
// emission exp(pred) applied input-side in f16 (X = a*ri*e) with a 3-buffer
// raw-prefetch + exp pipeline (backward stub previously had no prefetch).
// Readout MFMA replaced by a 16-FMA dot vs exp(T[.,end]).  zero_out merged
// into sort_k; combine gold-path fully unrolled (independent gathers).
constexpr int B_ = 512, S_ = 1024, L_ = 64, C_ = 66;
constexpr int K_ = 64, G_ = 32, STUB = 16, QMIN = 12;

typedef _Float16 half8 __attribute__((ext_vector_type(8)));
typedef _Float16 half4v __attribute__((ext_vector_type(4)));
typedef float f32x4 __attribute__((ext_vector_type(4)));

__device__ __forceinline__ f32x4 mfma16(half8 a, half8 b, f32x4 c){
  return __builtin_amdgcn_mfma_f32_16x16x32_f16(a, b, c, 0, 0, 0);
}
__device__ __forceinline__ float max4(const f32x4& a){
  return fmaxf(fmaxf(a[0], a[1]), fmaxf(a[2], a[3]));
}
__device__ __forceinline__ half8 splat8(_Float16 v){
  half8 r;
#pragma unroll
  for (int j = 0; j < 8; ++j) r[j] = v;
  return r;
}

// ---- bitonic sort of batches by seq_len (stable via idx) + out zero ----
__global__ __launch_bounds__(512) void sort_k(const int* __restrict__ seqlen,
                                              int* __restrict__ order,
                                              float* __restrict__ out){
  __shared__ int key[B_];
  const int i = threadIdx.x;
  if (i == 0) *out = 0.0f;
  key[i] = (seqlen[i] << 10) | i;
  __syncthreads();
  for (int kk = 2; kk <= B_; kk <<= 1)
    for (int j = kk >> 1; j > 0; j >>= 1){
      const int p = i ^ j;
      if (p > i){
        const int a = key[i], b = key[p];
        if ((a > b) == ((i & kk) == 0)){ key[i] = b; key[p] = a; }
      }
      __syncthreads();
    }
  order[i] = key[i] & 1023;
}

// ---- main: one wave per (group g, chunk k) ----
__global__ __launch_bounds__(64, 2) void crf_chunks_k(
    const float* __restrict__ pred, const int* __restrict__ seqlen,
    const float* __restrict__ trans, const int* __restrict__ order,
    float* __restrict__ wq, float* __restrict__ vhq,
    float* __restrict__ Zfq, float* __restrict__ Rq)
{
  const int g = blockIdx.x / K_;
  const int k = blockIdx.x - g * K_;
  const int lane = threadIdx.x;
  const int c  = lane & 15;        // chain / MFMA column
  const int q4 = lane >> 4;        // quad

  const int myb  = order[g * 16 + c];
  const int mysl = seqlen[myb];
  int msl = mysl;
#pragma unroll
  for (int off = 1; off < 16; off <<= 1){
    const int o = __shfl_xor(msl, off); msl = msl > o ? msl : o;
  }
  const int N  = msl - 1;                     // group's forward steps
  int q  = (N + K_ - 1) / K_;                 // rows per chunk
  if (q < QMIN) q = QMIN;                     // rank-1 accuracy floor
  const int r0 = 1 + k * q;                   // first row of this chunk
  int len = N - k * q; if (len < 0) len = 0; if (len > q) len = q;
  if (k > 0 && len == 0) return;              // inactive chunk (never read)

  const float* pb = pred + (size_t)myb * (S_ * L_);
  __shared__ __align__(16) _Float16 lds[16 * 72];
  _Float16* lw = &lds[72 * c];
  const f32x4 z4 = {0.f, 0.f, 0.f, 0.f};

  // unnormalized f16 write of C/D-layout acc (state d=16i+4q4+r), RTN cvts
  auto lds_wr = [&](const f32x4& A, int i){
    half4v h;
    h[0] = (_Float16)A[0]; h[1] = (_Float16)A[1];
    h[2] = (_Float16)A[2]; h[3] = (_Float16)A[3];
    *(half4v*)&lw[16*i + 4*q4] = h;           // ds_write_b64
  };
  auto lds_rd = [&](half8& R0, half8& R1){    // X-layout: [8q4..], [32+8q4..]
    R0 = *(const half8*)&lw[8*q4];
    R1 = *(const half8*)&lw[32 + 8*q4];
  };
  auto expcvt = [&](const f32x4* raw, half8& E0, half8& E1){
#pragma unroll
    for (int j = 0; j < 4; ++j){
      E0[j]   = (_Float16)__expf(raw[0][j]);
      E0[j+4] = (_Float16)__expf(raw[1][j]);
      E1[j]   = (_Float16)__expf(raw[2][j]);
      E1[j+4] = (_Float16)__expf(raw[3][j]);
    }
  };

  // ---------- backward stub (k>0): left direction of this chunk ----------
  if (k > 0){
    half8 Ab[4][2];
#pragma unroll
    for (int T = 0; T < 2; ++T)
#pragma unroll
      for (int R = 0; R < 4; ++R){
        half8 v;
#pragma unroll
        for (int jj = 0; jj < 8; ++jj)
          v[jj] = (_Float16)__expf(trans[(16*R + c)*C_ + 32*T + 8*q4 + jj]);
        Ab[R][T] = v;
      }
    half8 V0 = splat8((_Float16)1.0f), V1 = splat8((_Float16)1.0f);
    const int n = (len < STUB) ? len : STUB;  // q<=16 => full-chunk backward
    const int t0 = r0 + n - 1;
    auto ldB = [&](f32x4* raw, int t){
      const int tt = (t < r0) ? r0 : t;
      const f32x4* pl = (const f32x4*)(pb + (size_t)tt * L_);
      raw[0]=pl[2*q4]; raw[1]=pl[2*q4+1]; raw[2]=pl[8+2*q4]; raw[3]=pl[8+2*q4+1];
    };
    f32x4 rb0[4], rb1[4], rb2[4];
    half8 e00,e01,e10,e11,e20,e21;
    ldB(rb0, t0); ldB(rb1, t0-1); ldB(rb2, t0-2);
    expcvt(rb0, e00, e01);
    auto bstep = [&](f32x4* rld, const half8& E0, const half8& E1,
                     f32x4* rex, half8& Nx0, half8& Nx1, int t){
      const half8 Xb0 = V0 * E0, Xb1 = V1 * E1;       // input-side emission
      f32x4 a0=z4,a1=z4,a2=z4,a3=z4;
      a0 = mfma16(Ab[0][0],Xb0,a0); a0 = mfma16(Ab[0][1],Xb1,a0);
      a1 = mfma16(Ab[1][0],Xb0,a1); a1 = mfma16(Ab[1][1],Xb1,a1);
      a2 = mfma16(Ab[2][0],Xb0,a2); a2 = mfma16(Ab[2][1],Xb1,a2);
      a3 = mfma16(Ab[3][0],Xb0,a3); a3 = mfma16(Ab[3][1],Xb1,a3);
      lds_wr(a0,0); lds_wr(a1,1); lds_wr(a2,2); lds_wr(a3,3);
      float mx = fmaxf(fmaxf(max4(a0), max4(a1)), fmaxf(max4(a2), max4(a3)));
      mx = fmaxf(mx, __shfl_xor(mx, 16)); mx = fmaxf(mx, __shfl_xor(mx, 32));
      const float ri = __builtin_amdgcn_rcpf(mx);
      ldB(rld, t - 3);                                 // prefetch depth 3
      expcvt(rex, Nx0, Nx1);                           // e for next step
      asm volatile("s_waitcnt lgkmcnt(0)" ::: "memory");
      half8 R0, R1; lds_rd(R0, R1);
      const half8 rs = splat8((_Float16)ri);
      V0 = R0 * rs; V1 = R1 * rs;                      // deferred normalize
    };
    int s = 0;
    while (s < n){
      bstep(rb0, e00,e01, rb1, e10,e11, t0 - s); ++s; if (s >= n) break;
      bstep(rb1, e10,e11, rb2, e20,e21, t0 - s); ++s; if (s >= n) break;
      bstep(rb2, e20,e21, rb0, e00,e01, t0 - s); ++s;
    }
    float* dst = vhq + ((size_t)(g*K_ + k)*16 + c)*64;
    f32x4 o0,o1,o2,o3;
#pragma unroll
    for (int j=0;j<4;++j){ o0[j]=(float)V0[j]; o1[j]=(float)V0[j+4];
                           o2[j]=(float)V1[j]; o3[j]=(float)V1[j+4]; }
    *(f32x4*)&dst[8*q4] = o0;      *(f32x4*)&dst[8*q4+4] = o1;
    *(f32x4*)&dst[32+8*q4] = o2;   *(f32x4*)&dst[32+8*q4+4] = o3;
  }

  // ---------- forward A-frags + readout row (exp(T[.,end]), X-layout) ----
  half8 Af[4][2];
  float er0[8], er1[8];
#pragma unroll
  for (int T = 0; T < 2; ++T)
#pragma unroll
    for (int R = 0; R < 4; ++R){
      half8 v;
#pragma unroll
      for (int jj = 0; jj < 8; ++jj)
        v[jj] = (_Float16)__expf(trans[(32*T + 8*q4 + jj)*C_ + 16*R + c]);
      Af[R][T] = v;
    }
#pragma unroll
  for (int jj = 0; jj < 8; ++jj){
    er0[jj] = __expf(trans[(8*q4 + jj)*C_ + (L_ + 1)]);
    er1[jj] = __expf(trans[(32 + 8*q4 + jj)*C_ + (L_ + 1)]);
  }

  // ---------- init state ----------
  half8 X0, X1;
  float Z = 0.0f, Rsv = 0.0f;
  if (k == 0){
    const f32x4* pl = (const f32x4*)pb;   // pred row 0
    const f32x4 p0 = pl[2*q4], p1 = pl[2*q4+1], p2 = pl[8+2*q4], p3 = pl[8+2*q4+1];
    const float* ts = trans + L_ * C_;    // T[start][.]
    float av[16];
#pragma unroll
    for (int jj = 0; jj < 4; ++jj){
      av[jj]    = p0[jj] + ts[8*q4 + jj];
      av[jj+4]  = p1[jj] + ts[8*q4 + 4 + jj];
      av[jj+8]  = p2[jj] + ts[32 + 8*q4 + jj];
      av[jj+12] = p3[jj] + ts[32 + 8*q4 + 4 + jj];
    }
    float mx = av[0];
#pragma unroll
    for (int i = 1; i < 16; ++i) mx = fmaxf(mx, av[i]);
    mx = fmaxf(mx, __shfl_xor(mx, 16)); mx = fmaxf(mx, __shfl_xor(mx, 32));
    Z = mx;
    float dot = 0.f;
#pragma unroll
    for (int jj = 0; jj < 4; ++jj){
      const float x0 = __expf(av[jj]    - mx), x1 = __expf(av[jj+4]  - mx);
      const float x2 = __expf(av[jj+8]  - mx), x3 = __expf(av[jj+12] - mx);
      X0[jj] = (_Float16)x0; X0[jj+4] = (_Float16)x1;
      X1[jj] = (_Float16)x2; X1[jj+4] = (_Float16)x3;
      dot += x0*er0[jj] + x1*er0[jj+4] + x2*er1[jj] + x3*er1[jj+4];
    }
    dot += __shfl_xor(dot, 16); dot += __shfl_xor(dot, 32);
    if (mysl == 1) Rsv = __logf(dot) + Z;   // sl==1: answer from init state
  } else {
    X0 = splat8((_Float16)1.0f); X1 = splat8((_Float16)1.0f);
  }

  // ---------- forward chunk ----------
  if (len > 0){
    const int tmax = r0 + len - 1;
    auto ldF = [&](f32x4* raw, int t){
      const int tt = (t > tmax) ? tmax : t;
      const f32x4* pl = (const f32x4*)(pb + (size_t)tt * L_);
      raw[0]=pl[2*q4]; raw[1]=pl[2*q4+1]; raw[2]=pl[8+2*q4]; raw[3]=pl[8+2*q4+1];
    };
    f32x4 rf0[4], rf1[4], rf2[4];
    half8 f00,f01,f10,f11,f20,f21;
    ldF(rf0, r0); ldF(rf1, r0+1); ldF(rf2, r0+2);
    expcvt(rf0, f00, f01);

    auto dostep = [&](f32x4* rld, const half8& E0, const half8& E1,
                      f32x4* rex, half8& Nx0, half8& Nx1, int t){
      f32x4 a0=z4,a1=z4,a2=z4,a3=z4;
      a0 = mfma16(Af[0][0],X0,a0); a0 = mfma16(Af[0][1],X1,a0);
      a1 = mfma16(Af[1][0],X0,a1); a1 = mfma16(Af[1][1],X1,a1);
      a2 = mfma16(Af[2][0],X0,a2); a2 = mfma16(Af[2][1],X1,a2);
      a3 = mfma16(Af[3][0],X0,a3); a3 = mfma16(Af[3][1],X1,a3);
      lds_wr(a0,0); lds_wr(a1,1); lds_wr(a2,2); lds_wr(a3,3);
      float mx = fmaxf(fmaxf(max4(a0), max4(a1)), fmaxf(max4(a2), max4(a3)));
      mx = fmaxf(mx, __shfl_xor(mx, 16)); mx = fmaxf(mx, __shfl_xor(mx, 32));
      const float ri = __builtin_amdgcn_rcpf(mx);
      Z += __logf(mx);
      ldF(rld, t + 3);                                 // prefetch depth 3
      expcvt(rex, Nx0, Nx1);                           // e for next step
      asm volatile("s_waitcnt lgkmcnt(0)" ::: "memory");
      half8 R0, R1; lds_rd(R0, R1);
      const half8 rs = splat8((_Float16)ri);
      X0 = R0 * rs * E0;  X1 = R1 * rs * E1;           // normalize + emission
      if (__any(t == mysl - 1)){                       // readout dot (no MFMA)
        float dot = 0.f;
#pragma unroll
        for (int jj = 0; jj < 8; ++jj)
          dot += (float)X0[jj]*er0[jj] + (float)X1[jj]*er1[jj];
        dot += __shfl_xor(dot, 16); dot += __shfl_xor(dot, 32);
        Rsv = (t == mysl - 1) ? (__logf(dot) + Z) : Rsv;
      }
    };

    int s = 0;
    while (s < len){
      dostep(rf0, f00,f01, rf1, f10,f11, r0 + s); ++s; if (s >= len) break;
      dostep(rf1, f10,f11, rf2, f20,f21, r0 + s); ++s; if (s >= len) break;
      dostep(rf2, f20,f21, rf0, f00,f01, r0 + s); ++s;
    }
    // store w = final normalized state (f16 regs -> f32, X-layout)
    float* dst = wq + ((size_t)(g*K_ + k)*16 + c)*64;
    f32x4 o0,o1,o2,o3;
#pragma unroll
    for (int j=0;j<4;++j){ o0[j]=(float)X0[j]; o1[j]=(float)X0[j+4];
                           o2[j]=(float)X1[j]; o3[j]=(float)X1[j+4]; }
    *(f32x4*)&dst[8*q4] = o0;      *(f32x4*)&dst[8*q4+4] = o1;
    *(f32x4*)&dst[32+8*q4] = o2;   *(f32x4*)&dst[32+8*q4+4] = o3;
  }

  if (lane < 16){
    Zfq[(g*K_ + k)*16 + c] = Z;
    Rq [(g*K_ + k)*16 + c] = Rsv;
  }
}

// ---- combine + gold: one wave per sorted position, lane-parallel chunks ----
__global__ __launch_bounds__(64) void crf_combine_k(
    const float* __restrict__ pred, const int* __restrict__ ref,
    const int* __restrict__ seqlen, const float* __restrict__ trans,
    const int* __restrict__ order, const float* __restrict__ wq,
    const float* __restrict__ vhq, const float* __restrict__ Zfq,
    const float* __restrict__ Rq, float* __restrict__ out)
{
  const int p = blockIdx.x, lane = threadIdx.x;
  const int g = p >> 4;
  const int myb = order[p];
  const int sl  = seqlen[myb];
  int msl = seqlen[order[g*16 + (lane & 15)]];
#pragma unroll
  for (int off = 1; off < 16; off <<= 1){
    const int o = __shfl_xor(msl, off); msl = msl > o ? msl : o;
  }
  const int N = msl - 1;
  int q = (N + K_ - 1) / K_;
  if (q < QMIN) q = QMIN;
  const int kc = (sl <= 1) ? 0 : (sl - 2) / q;   // kc <= 63 < 64 lanes
  const int c = p & 15;

  // lane l owns boundary l: contrib = log(v_l . w_{l-1}) - log(v_l . 1) + Zf[l-1]
  float contrib = 0.0f;
  if (lane >= 1 && lane <= kc){
    const float* vv = vhq + ((size_t)(g*K_ + lane)*16 + c)*64;
    const float* ww = wq  + ((size_t)(g*K_ + lane - 1)*16 + c)*64;
    float d1 = 0.0f, d0 = 0.0f;
#pragma unroll
    for (int j = 0; j < 16; ++j){
      const f32x4 a = *(const f32x4*)&vv[4*j];
      const f32x4 b = *(const f32x4*)&ww[4*j];
#pragma unroll
      for (int r = 0; r < 4; ++r){ d1 += a[r]*b[r]; d0 += a[r]; }
    }
    contrib = __logf(d1) - __logf(d0) + Zfq[(g*K_ + lane - 1)*16 + c];
  }
  if (lane == 0) contrib = Rq[(g*K_ + kc)*16 + c];

  // gold path — fully unrolled so the 16 strided gathers are independent
  const float* prow = pred + (size_t)myb * (S_ * L_);
  const int* rrow = ref + (size_t)myb * S_;
  float gold = 0.0f;
#pragma unroll
  for (int i = 0; i < 16; ++i){
    const int tt = lane + 64*i;
    if (tt < sl){
      const int r  = rrow[tt];
      const int pr = (tt == 0) ? L_ : rrow[tt - 1];
      float x = prow[tt * L_ + r] + trans[pr * C_ + r];
      if (tt == sl - 1) x += trans[r * C_ + (L_ + 1)];
      gold += x;
    }
  }
  float val = contrib - gold;
#pragma unroll
  for (int off = 32; off >= 1; off >>= 1) val += __shfl_xor(val, off);
  if (lane == 0) atomicAdd(out, val);
}

extern "C" void kernel_launch(void* const* d_in, const int* in_sizes, int n_in,
                              void* d_out, int out_size, void* d_ws, size_t ws_size,
                              hipStream_t stream) {
  const float* pred   = (const float*)d_in[0];
  const int*   ref    = (const int*)d_in[1];
  const int*   seqlen = (const int*)d_in[2];
  const float* trans  = (const float*)d_in[3];
  float* out = (float*)d_out;

  int*   order = (int*)d_ws;
  float* base  = (float*)d_ws;
  float* w  = base + 1024;            // [G][K][16][64]  (8.4 MB)
  float* vh = w + G_*K_*16*64;        // [G][K][16][64]  (8.4 MB)
  float* Zf = vh + G_*K_*16*64;       // [G][K][16]
  float* Rr = Zf + G_*K_*16;          // [G][K][16]

  sort_k<<<1, 512, 0, stream>>>(seqlen, order, out);
  crf_chunks_k<<<G_*K_, 64, 0, stream>>>(pred, seqlen, trans, order, w, vh, Zf, Rr);
  crf_combine_k<<<B_, 64, 0, stream>>>(pred, ref, seqlen, trans, order, w, vh, Zf, Rr, out);
}